// Round 4
// baseline (2167.229 us; speedup 1.0000x reference)
//
#include <hip/hip_runtime.h>
#include <cstdint>
#include <cstddef>

#define NNODES 50000
#define NREL   16
#define DIM    200
#define NEDGE  400000
#define NBLK   782                      // ceil(NNODES/64)
#define NKEY   (NBLK * 1024)            // 800768, key = (dst>>6)*1024 + r*64 + (dst&63)
#define NPART  (NKEY / 256)             // 3128
#define WTN    208                      // padded n (13 x 16)
#define WTK    224                      // padded k (7 x 32)
#define WTSZ   (17 * WTN * WTK)
#define PERM_CAP 1024                   // block degree: mean 512, sd ~23 -> cap safe

typedef __attribute__((ext_vector_type(8))) short short8;   // 8 bf16
typedef __attribute__((ext_vector_type(4))) float floatx4;  // MFMA C/D

__device__ __forceinline__ unsigned short f2bf(float f) {
    unsigned int u = __float_as_uint(f);
    u = (u + 0x7FFFu + ((u >> 16) & 1u)) >> 16;   // RNE
    return (unsigned short)u;
}
__device__ __forceinline__ float bf2f(unsigned short h) {
    return __uint_as_float(((unsigned int)h) << 16);
}

// ---------- preprocessing: counting sort by block-major key ----------

__device__ __forceinline__ int edge_key(int d, int r) {
    return (d >> 6) * 1024 + r * 64 + (d & 63);
}

__global__ void count_kernel(const int* __restrict__ ei, const int* __restrict__ et,
                             int* __restrict__ cnt) {
    int e = blockIdx.x * 256 + threadIdx.x;
    if (e < NEDGE) atomicAdd(&cnt[edge_key(ei[NEDGE + e], et[e])], 1);
}

__global__ void scan1_kernel(const int* __restrict__ cnt, int* __restrict__ rp,
                             int* __restrict__ part) {
    __shared__ int sc[256];
    int b = blockIdx.x, t = threadIdx.x, i = b * 256 + t;
    int v = cnt[i];
    sc[t] = v; __syncthreads();
    for (int off = 1; off < 256; off <<= 1) {
        int x = (t >= off) ? sc[t - off] : 0;
        __syncthreads();
        sc[t] += x;
        __syncthreads();
    }
    int incl = sc[t];
    rp[i] = incl - v;
    if (t == 255) part[b] = incl;
}

__global__ void scan2_kernel(int* __restrict__ p) {
    __shared__ int sc[256];
    __shared__ int carry_s;
    int t = threadIdx.x;
    if (t == 0) carry_s = 0;
    __syncthreads();
    for (int base = 0; base < NPART; base += 256) {
        int i = base + t;
        int v = (i < NPART) ? p[i] : 0;
        sc[t] = v; __syncthreads();
        for (int off = 1; off < 256; off <<= 1) {
            int x = (t >= off) ? sc[t - off] : 0;
            __syncthreads();
            sc[t] += x;
            __syncthreads();
        }
        int incl = sc[t];
        int carry = carry_s;
        if (i < NPART) p[i] = carry + incl - v;
        __syncthreads();
        if (t == 255) carry_s = carry + incl;
        __syncthreads();
    }
    if (t == 0) p[NPART] = carry_s;   // == NEDGE
}

__global__ void scan3_kernel(int* __restrict__ rp, int* __restrict__ cursor,
                             const int* __restrict__ part) {
    int i = blockIdx.x * 256 + threadIdx.x;
    if (i < NKEY) {
        int v = rp[i] + part[i >> 8];
        rp[i] = v;
        cursor[i] = v;
    } else if (i == NKEY) {
        rp[i] = part[NPART];
    }
}

// perm[pos] = (row_in_block << 16) | src   (src < 50000 fits 16 bits)
__global__ void scatter_kernel(const int* __restrict__ ei, const int* __restrict__ et,
                               int* __restrict__ cursor, int* __restrict__ perm) {
    int e = blockIdx.x * 256 + threadIdx.x;
    if (e < NEDGE) {
        int d = ei[NEDGE + e];
        int pos = atomicAdd(&cursor[edge_key(d, et[e])], 1);
        perm[pos] = ((d & 63) << 16) | ei[e];
    }
}

// ---------- W^T prep: WT[r][n][k] bf16, zero-padded; r==16 is root ----------
__global__ void wt_kernel(const float* __restrict__ W, const float* __restrict__ root,
                          unsigned short* __restrict__ WT) {
    int idx = blockIdx.x * 256 + threadIdx.x;
    if (idx >= WTSZ) return;
    int r = idx / (WTN * WTK);
    int rem = idx - r * (WTN * WTK);
    int n = rem / WTK;
    int k = rem - n * WTK;
    float v = 0.f;
    if (n < DIM && k < DIM)
        v = (r < 16) ? W[((size_t)r * DIM + k) * DIM + n] : root[(size_t)k * DIM + n];
    WT[idx] = f2bf(v);
}

// ---------- fused layer ----------
// Edge-parallel gather into fp32 LDS accumulator + MFMA. 2 barriers per chunk.
template<bool SRC_F32, bool OUT_RELU_BF16>
__global__ __launch_bounds__(256) void fused_kernel(
        const void* __restrict__ srcv, const unsigned short* __restrict__ WT,
        const int* __restrict__ rp, const int* __restrict__ perm,
        const float* __restrict__ bias, void* __restrict__ outv) {
    __shared__ __align__(16) float Af[64 * DIM];   // 51,200 B fp32 accumulator
    __shared__ int s_rp[1025];
    __shared__ int s_perm[PERM_CAP];
    const int t = threadIdx.x;
    const int w = t >> 6;
    const int lane = t & 63;
    const int quad = lane >> 4;
    const int mn = lane & 15;
    const int v0 = blockIdx.x * 64;
    const int kbase = blockIdx.x * 1024;
    const bool colok = (lane < 50);

    for (int i = t; i < 1025; i += 256) s_rp[i] = rp[kbase + i];
    for (int i = t; i < 64 * DIM / 4; i += 256)
        ((float4*)Af)[i] = make_float4(0.f, 0.f, 0.f, 0.f);
    __syncthreads();
    const int eStart = s_rp[0];
    const int nE = s_rp[1024] - eStart;
    for (int i = t; i < nE && i < PERM_CAP; i += 256) s_perm[i] = perm[eStart + i];
    __syncthreads();

    const float* srcf = (const float*)srcv;
    const unsigned short* srcb = (const unsigned short*)srcv;

    floatx4 acc[13];
    #pragma unroll
    for (int i = 0; i < 13; ++i) acc[i] = (floatx4){0.f, 0.f, 0.f, 0.f};

    auto ldrow = [&](int node) -> float4 {
        if (SRC_F32) {
            return *(const float4*)(srcf + (size_t)node * DIM + (lane << 2));
        } else {
            ushort4 u = *(const ushort4*)(srcb + (size_t)node * DIM + (lane << 2));
            return make_float4(bf2f(u.x), bf2f(u.y), bf2f(u.z), bf2f(u.w));
        }
    };

    for (int r = 0; r < 17; ++r) {
        // ---- phase 1: fill Af (edge-parallel atomics / root direct) ----
        if (r < 16) {
            const int cs = __builtin_amdgcn_readfirstlane(s_rp[r << 6]);
            const int ce = __builtin_amdgcn_readfirstlane(s_rp[(r << 6) + 64]);
            for (int j = cs + w; j < ce; j += 4) {
                int idx = j - eStart;
                int p = (idx < PERM_CAP) ? s_perm[idx] : perm[j];
                int sv = p & 0xFFFF;
                int m  = p >> 16;
                if (colok) {
                    float4 f = ldrow(sv);
                    float* d = &Af[m * DIM + (lane << 2)];
                    atomicAdd(d + 0, f.x);
                    atomicAdd(d + 1, f.y);
                    atomicAdd(d + 2, f.z);
                    atomicAdd(d + 3, f.w);
                }
            }
        } else {
            #pragma unroll
            for (int i = 0; i < 16; ++i) {
                int m = (w << 4) + i;
                int v = v0 + m;
                if (v < NNODES && colok) {
                    float4 f = ldrow(v);
                    *(float4*)&Af[m * DIM + (lane << 2)] = f;
                }
            }
        }
        __syncthreads();
        // ---- phase 2: readout + zero (fused) + convert ----
        float sc;
        {
            int m = (w << 4) + mn;
            if (r < 16) {
                int kk = (r << 6) + m;
                int c = s_rp[kk + 1] - s_rp[kk];
                sc = (c > 0) ? 1.0f / (float)c : 0.0f;
            } else sc = 1.0f;
        }
        const int arow = ((w << 4) + mn) * DIM + (quad << 3);
        short8 af[7];
        #pragma unroll
        for (int ks = 0; ks < 7; ++ks) {
            short8 a;
            if (ks < 6 || quad == 0) {   // ks==6, quad>0 is pure k-pad
                float4 q0 = *(float4*)&Af[arow + ks * 32];
                float4 q1 = *(float4*)&Af[arow + ks * 32 + 4];
                *(float4*)&Af[arow + ks * 32]     = make_float4(0.f, 0.f, 0.f, 0.f);
                *(float4*)&Af[arow + ks * 32 + 4] = make_float4(0.f, 0.f, 0.f, 0.f);
                a[0] = (short)f2bf(q0.x * sc); a[1] = (short)f2bf(q0.y * sc);
                a[2] = (short)f2bf(q0.z * sc); a[3] = (short)f2bf(q0.w * sc);
                a[4] = (short)f2bf(q1.x * sc); a[5] = (short)f2bf(q1.y * sc);
                a[6] = (short)f2bf(q1.z * sc); a[7] = (short)f2bf(q1.w * sc);
            } else {
                a = (short8){0, 0, 0, 0, 0, 0, 0, 0};
            }
            af[ks] = a;
        }
        __syncthreads();
        // ---- phase 3: MFMA (registers + L2-resident B) ----
        const char* WTr = (const char*)WT + (size_t)r * (WTN * WTK * 2);
        const char* brow = WTr + (size_t)mn * (WTK * 2) + (quad << 4);
        #pragma unroll
        for (int ks = 0; ks < 7; ++ks) {
            #pragma unroll
            for (int nt = 0; nt < 13; ++nt) {
                const short8 bf = *(const short8*)(brow + ks * 64 + nt * (16 * WTK * 2));
                acc[nt] = __builtin_amdgcn_mfma_f32_16x16x32_bf16(af[ks], bf, acc[nt], 0, 0, 0);
            }
        }
    }

    // ---- epilogue: C row = quad*4 + i, col = nt*16 + mn ----
    float* outf = (float*)outv;
    unsigned short* outb = (unsigned short*)outv;
    #pragma unroll
    for (int nt = 0; nt < 13; ++nt) {
        const int col = nt * 16 + mn;
        if (col < DIM) {
            const float bv = bias[col];
            #pragma unroll
            for (int i = 0; i < 4; ++i) {
                const int v = v0 + (w << 4) + (quad << 2) + i;
                if (v < NNODES) {
                    float x = acc[nt][i] + bv;
                    if (OUT_RELU_BF16) {
                        x = fmaxf(x, 0.f);
                        outb[(size_t)v * DIM + col] = f2bf(x);
                    } else {
                        outf[(size_t)v * DIM + col] = x;
                    }
                }
            }
        }
    }
}

// ---------- launch ----------

extern "C" void kernel_launch(void* const* d_in, const int* in_sizes, int n_in,
                              void* d_out, int out_size, void* d_ws, size_t ws_size,
                              hipStream_t stream) {
    const int*   edge_index = (const int*)d_in[0];
    const int*   edge_type  = (const int*)d_in[1];
    const float* emb   = (const float*)d_in[2];
    const float* W1    = (const float*)d_in[3];
    const float* root1 = (const float*)d_in[4];
    const float* b1    = (const float*)d_in[5];
    const float* W2    = (const float*)d_in[6];
    const float* root2 = (const float*)d_in[7];
    const float* b2    = (const float*)d_in[8];
    float* out = (float*)d_out;

    // ws layout (bytes):
    //  cnt/cursor  0           3,203,072   (cnt dead after scan1; reused as cursor)
    //  rp          3,203,072   3,203,080
    //  part        6,406,152      12,520
    //  perm        6,418,672   1,600,000
    //  hbf         8,018,672  20,000,000
    //  WT1        28,018,672   1,584,128
    //  WT2        29,602,800   1,584,128   -> total ~31.2 MB
    char* ws = (char*)d_ws;
    int*            cnt    = (int*)(ws);
    int*            cursor = (int*)(ws);
    int*            rp     = (int*)(ws + 3203072);
    int*            part   = (int*)(ws + 6406152);
    int*            perm   = (int*)(ws + 6418672);
    unsigned short* hbf    = (unsigned short*)(ws + 8018672);
    unsigned short* WT1    = (unsigned short*)(ws + 28018672);
    unsigned short* WT2    = (unsigned short*)(ws + 29602800);

    hipMemsetAsync(cnt, 0, (size_t)NKEY * sizeof(int), stream);
    count_kernel<<<(NEDGE + 255) / 256, 256, 0, stream>>>(edge_index, edge_type, cnt);
    scan1_kernel<<<NPART, 256, 0, stream>>>(cnt, rp, part);
    scan2_kernel<<<1, 256, 0, stream>>>(part);
    scan3_kernel<<<(NKEY + 256) / 256 + 1, 256, 0, stream>>>(rp, cursor, part);
    scatter_kernel<<<(NEDGE + 255) / 256, 256, 0, stream>>>(edge_index, edge_type, cursor, perm);

    wt_kernel<<<(WTSZ + 255) / 256, 256, 0, stream>>>(W1, root1, WT1);
    wt_kernel<<<(WTSZ + 255) / 256, 256, 0, stream>>>(W2, root2, WT2);

    fused_kernel<true, true><<<NBLK, 256, 0, stream>>>(emb, WT1, rp, perm, b1, hbf);
    fused_kernel<false, false><<<NBLK, 256, 0, stream>>>(hbf, WT2, rp, perm, b2, out);
}

// Round 5
// 2163.695 us; speedup vs baseline: 1.0016x; 1.0016x over previous
//
#include <hip/hip_runtime.h>
#include <cstdint>
#include <cstddef>

#define NNODES 50000
#define NREL   16
#define DIM    200
#define NEDGE  400000
#define NBLK   782                      // ceil(NNODES/64)
#define NKEY   (NBLK * 1024)            // 800768, key = (dst>>6)*1024 + r*64 + (dst&63)
#define NPART  (NKEY / 256)             // 3128
#define WTN    208                      // padded n (13 x 16)
#define WTK    224                      // padded k (7 x 32)
#define WTSZ   (17 * WTN * WTK)
#define PERM_CAP 1024                   // block degree: mean 512, sd ~23 -> cap safe
#define AFS    204                      // Af row stride (floats): 204 breaks 8-way b128 conflicts
#define MAXE   16                       // per-wave per-chunk batched edges (P(overflow) ~ 0.4%)

typedef __attribute__((ext_vector_type(8))) short short8;   // 8 bf16
typedef __attribute__((ext_vector_type(4))) float floatx4;  // MFMA C/D

__device__ __forceinline__ unsigned short f2bf(float f) {
    unsigned int u = __float_as_uint(f);
    u = (u + 0x7FFFu + ((u >> 16) & 1u)) >> 16;   // RNE
    return (unsigned short)u;
}
__device__ __forceinline__ float bf2f(unsigned short h) {
    return __uint_as_float(((unsigned int)h) << 16);
}

// ---------- preprocessing: counting sort by block-major key ----------

__device__ __forceinline__ int edge_key(int d, int r) {
    return (d >> 6) * 1024 + r * 64 + (d & 63);
}

__global__ void count_kernel(const int* __restrict__ ei, const int* __restrict__ et,
                             int* __restrict__ cnt) {
    int e = blockIdx.x * 256 + threadIdx.x;
    if (e < NEDGE) atomicAdd(&cnt[edge_key(ei[NEDGE + e], et[e])], 1);
}

__global__ void scan1_kernel(const int* __restrict__ cnt, int* __restrict__ rp,
                             int* __restrict__ part) {
    __shared__ int sc[256];
    int b = blockIdx.x, t = threadIdx.x, i = b * 256 + t;
    int v = cnt[i];
    sc[t] = v; __syncthreads();
    for (int off = 1; off < 256; off <<= 1) {
        int x = (t >= off) ? sc[t - off] : 0;
        __syncthreads();
        sc[t] += x;
        __syncthreads();
    }
    int incl = sc[t];
    rp[i] = incl - v;
    if (t == 255) part[b] = incl;
}

__global__ void scan2_kernel(int* __restrict__ p) {
    __shared__ int sc[256];
    __shared__ int carry_s;
    int t = threadIdx.x;
    if (t == 0) carry_s = 0;
    __syncthreads();
    for (int base = 0; base < NPART; base += 256) {
        int i = base + t;
        int v = (i < NPART) ? p[i] : 0;
        sc[t] = v; __syncthreads();
        for (int off = 1; off < 256; off <<= 1) {
            int x = (t >= off) ? sc[t - off] : 0;
            __syncthreads();
            sc[t] += x;
            __syncthreads();
        }
        int incl = sc[t];
        int carry = carry_s;
        if (i < NPART) p[i] = carry + incl - v;
        __syncthreads();
        if (t == 255) carry_s = carry + incl;
        __syncthreads();
    }
    if (t == 0) p[NPART] = carry_s;   // == NEDGE
}

__global__ void scan3_kernel(int* __restrict__ rp, int* __restrict__ cursor,
                             const int* __restrict__ part) {
    int i = blockIdx.x * 256 + threadIdx.x;
    if (i < NKEY) {
        int v = rp[i] + part[i >> 8];
        rp[i] = v;
        cursor[i] = v;
    } else if (i == NKEY) {
        rp[i] = part[NPART];
    }
}

// perm[pos] = (row_in_block << 16) | src   (src < 50000 fits 16 bits)
__global__ void scatter_kernel(const int* __restrict__ ei, const int* __restrict__ et,
                               int* __restrict__ cursor, int* __restrict__ perm) {
    int e = blockIdx.x * 256 + threadIdx.x;
    if (e < NEDGE) {
        int d = ei[NEDGE + e];
        int pos = atomicAdd(&cursor[edge_key(d, et[e])], 1);
        perm[pos] = ((d & 63) << 16) | ei[e];
    }
}

// ---------- W^T prep: WT[r][n][k] bf16, zero-padded; r==16 is root ----------
__global__ void wt_kernel(const float* __restrict__ W, const float* __restrict__ root,
                          unsigned short* __restrict__ WT) {
    int idx = blockIdx.x * 256 + threadIdx.x;
    if (idx >= WTSZ) return;
    int r = idx / (WTN * WTK);
    int rem = idx - r * (WTN * WTK);
    int n = rem / WTK;
    int k = rem - n * WTK;
    float v = 0.f;
    if (n < DIM && k < DIM)
        v = (r < 16) ? W[((size_t)r * DIM + k) * DIM + n] : root[(size_t)k * DIM + n];
    WT[idx] = f2bf(v);
}

// ---------- fused layer ----------
// Phase 1 batches all of a wave's chunk edges into VGPRs (16 loads in flight)
// before the LDS-atomic accumulate. 2 barriers per chunk.
template<bool SRC_F32, bool OUT_RELU_BF16>
__global__ __launch_bounds__(256, 2) void fused_kernel(
        const void* __restrict__ srcv, const unsigned short* __restrict__ WT,
        const int* __restrict__ rp, const int* __restrict__ perm,
        const float* __restrict__ bias, void* __restrict__ outv) {
    __shared__ __align__(16) float Af[64 * AFS];   // 52,224 B fp32 accumulator
    __shared__ int s_rp[1025];
    __shared__ int s_perm[PERM_CAP];
    const int t = threadIdx.x;
    const int w = t >> 6;
    const int lane = t & 63;
    const int quad = lane >> 4;
    const int mn = lane & 15;
    const int v0 = blockIdx.x * 64;
    const int kbase = blockIdx.x * 1024;
    const bool colok = (lane < 50);

    for (int i = t; i < 1025; i += 256) s_rp[i] = rp[kbase + i];
    for (int i = t; i < 64 * AFS / 4; i += 256)
        ((float4*)Af)[i] = make_float4(0.f, 0.f, 0.f, 0.f);
    __syncthreads();
    const int eStart = s_rp[0];
    const int nE = s_rp[1024] - eStart;
    for (int i = t; i < nE && i < PERM_CAP; i += 256) s_perm[i] = perm[eStart + i];
    __syncthreads();

    const float* srcf = (const float*)srcv;
    const unsigned short* srcb = (const unsigned short*)srcv;

    floatx4 acc[13];
    #pragma unroll
    for (int i = 0; i < 13; ++i) acc[i] = (floatx4){0.f, 0.f, 0.f, 0.f};

    auto ldrow = [&](int node) -> float4 {
        if (SRC_F32) {
            return *(const float4*)(srcf + (size_t)node * DIM + (lane << 2));
        } else {
            ushort4 u = *(const ushort4*)(srcb + (size_t)node * DIM + (lane << 2));
            return make_float4(bf2f(u.x), bf2f(u.y), bf2f(u.z), bf2f(u.w));
        }
    };

    for (int r = 0; r < 17; ++r) {
        // ---- phase 1: fill Af ----
        if (r < 16) {
            const int cs = __builtin_amdgcn_readfirstlane(s_rp[r << 6]);
            const int ce = __builtin_amdgcn_readfirstlane(s_rp[(r << 6) + 64]);
            const int cnt = ce - cs;
            const int base = cs - eStart;                 // block-local edge index
            const int nmine = (cnt > w) ? ((cnt - w + 3) >> 2) : 0;
            float4 q[MAXE];
            int    pm[MAXE];
            // issue all loads back-to-back (independent -> 16 in flight)
            #pragma unroll
            for (int i = 0; i < MAXE; ++i) {
                if (i < nmine) {
                    int li = base + w + (i << 2);
                    pm[i] = (li < PERM_CAP) ? s_perm[li] : perm[eStart + li];
                    if (colok) q[i] = ldrow(pm[i] & 0xFFFF);
                }
            }
            // accumulate as results drain
            #pragma unroll
            for (int i = 0; i < MAXE; ++i) {
                if (i < nmine && colok) {
                    float* d = &Af[(pm[i] >> 16) * AFS + (lane << 2)];
                    atomicAdd(d + 0, q[i].x);
                    atomicAdd(d + 1, q[i].y);
                    atomicAdd(d + 2, q[i].z);
                    atomicAdd(d + 3, q[i].w);
                }
            }
            // rare overflow (wave deg > MAXE): serial fallback
            for (int j = cs + 4 * MAXE + w; j < ce; j += 4) {
                int li = j - eStart;
                int p = (li < PERM_CAP) ? s_perm[li] : perm[j];
                if (colok) {
                    float4 f = ldrow(p & 0xFFFF);
                    float* d = &Af[(p >> 16) * AFS + (lane << 2)];
                    atomicAdd(d + 0, f.x); atomicAdd(d + 1, f.y);
                    atomicAdd(d + 2, f.z); atomicAdd(d + 3, f.w);
                }
            }
        } else {   // root chunk: direct row copy
            #pragma unroll
            for (int i = 0; i < 16; ++i) {
                int m = (w << 4) + i;
                int v = v0 + m;
                if (v < NNODES && colok) {
                    float4 f = ldrow(v);
                    *(float4*)&Af[m * AFS + (lane << 2)] = f;
                }
            }
        }
        __syncthreads();
        // ---- phase 2: readout + zero (fused) + convert ----
        float sc;
        {
            int m = (w << 4) + mn;
            if (r < 16) {
                int kk = (r << 6) + m;
                int c = s_rp[kk + 1] - s_rp[kk];
                sc = (c > 0) ? 1.0f / (float)c : 0.0f;
            } else sc = 1.0f;
        }
        const int arow = ((w << 4) + mn) * AFS + (quad << 3);
        short8 af[7];
        #pragma unroll
        for (int ks = 0; ks < 7; ++ks) {
            short8 a;
            if (ks < 6 || quad == 0) {   // ks==6, quad>0 is pure k-pad
                float4 q0 = *(float4*)&Af[arow + ks * 32];
                float4 q1 = *(float4*)&Af[arow + ks * 32 + 4];
                *(float4*)&Af[arow + ks * 32]     = make_float4(0.f, 0.f, 0.f, 0.f);
                *(float4*)&Af[arow + ks * 32 + 4] = make_float4(0.f, 0.f, 0.f, 0.f);
                a[0] = (short)f2bf(q0.x * sc); a[1] = (short)f2bf(q0.y * sc);
                a[2] = (short)f2bf(q0.z * sc); a[3] = (short)f2bf(q0.w * sc);
                a[4] = (short)f2bf(q1.x * sc); a[5] = (short)f2bf(q1.y * sc);
                a[6] = (short)f2bf(q1.z * sc); a[7] = (short)f2bf(q1.w * sc);
            } else {
                a = (short8){0, 0, 0, 0, 0, 0, 0, 0};
            }
            af[ks] = a;
        }
        __syncthreads();
        // ---- phase 3: MFMA (registers + L2-resident B) ----
        const char* WTr = (const char*)WT + (size_t)r * (WTN * WTK * 2);
        const char* brow = WTr + (size_t)mn * (WTK * 2) + (quad << 4);
        #pragma unroll
        for (int ks = 0; ks < 7; ++ks) {
            #pragma unroll
            for (int nt = 0; nt < 13; ++nt) {
                const short8 bf = *(const short8*)(brow + ks * 64 + nt * (16 * WTK * 2));
                acc[nt] = __builtin_amdgcn_mfma_f32_16x16x32_bf16(af[ks], bf, acc[nt], 0, 0, 0);
            }
        }
    }

    // ---- epilogue: C row = quad*4 + i, col = nt*16 + mn ----
    float* outf = (float*)outv;
    unsigned short* outb = (unsigned short*)outv;
    #pragma unroll
    for (int nt = 0; nt < 13; ++nt) {
        const int col = nt * 16 + mn;
        if (col < DIM) {
            const float bv = bias[col];
            #pragma unroll
            for (int i = 0; i < 4; ++i) {
                const int v = v0 + (w << 4) + (quad << 2) + i;
                if (v < NNODES) {
                    float x = acc[nt][i] + bv;
                    if (OUT_RELU_BF16) {
                        x = fmaxf(x, 0.f);
                        outb[(size_t)v * DIM + col] = f2bf(x);
                    } else {
                        outf[(size_t)v * DIM + col] = x;
                    }
                }
            }
        }
    }
}

// ---------- launch ----------

extern "C" void kernel_launch(void* const* d_in, const int* in_sizes, int n_in,
                              void* d_out, int out_size, void* d_ws, size_t ws_size,
                              hipStream_t stream) {
    const int*   edge_index = (const int*)d_in[0];
    const int*   edge_type  = (const int*)d_in[1];
    const float* emb   = (const float*)d_in[2];
    const float* W1    = (const float*)d_in[3];
    const float* root1 = (const float*)d_in[4];
    const float* b1    = (const float*)d_in[5];
    const float* W2    = (const float*)d_in[6];
    const float* root2 = (const float*)d_in[7];
    const float* b2    = (const float*)d_in[8];
    float* out = (float*)d_out;

    // ws layout (bytes):
    //  cnt/cursor  0           3,203,072   (cnt dead after scan1; reused as cursor)
    //  rp          3,203,072   3,203,080
    //  part        6,406,152      12,520
    //  perm        6,418,672   1,600,000
    //  hbf         8,018,672  20,000,000
    //  WT1        28,018,672   1,584,128
    //  WT2        29,602,800   1,584,128   -> total ~31.2 MB
    char* ws = (char*)d_ws;
    int*            cnt    = (int*)(ws);
    int*            cursor = (int*)(ws);
    int*            rp     = (int*)(ws + 3203072);
    int*            part   = (int*)(ws + 6406152);
    int*            perm   = (int*)(ws + 6418672);
    unsigned short* hbf    = (unsigned short*)(ws + 8018672);
    unsigned short* WT1    = (unsigned short*)(ws + 28018672);
    unsigned short* WT2    = (unsigned short*)(ws + 29602800);

    hipMemsetAsync(cnt, 0, (size_t)NKEY * sizeof(int), stream);
    count_kernel<<<(NEDGE + 255) / 256, 256, 0, stream>>>(edge_index, edge_type, cnt);
    scan1_kernel<<<NPART, 256, 0, stream>>>(cnt, rp, part);
    scan2_kernel<<<1, 256, 0, stream>>>(part);
    scan3_kernel<<<(NKEY + 256) / 256 + 1, 256, 0, stream>>>(rp, cursor, part);
    scatter_kernel<<<(NEDGE + 255) / 256, 256, 0, stream>>>(edge_index, edge_type, cursor, perm);

    wt_kernel<<<(WTSZ + 255) / 256, 256, 0, stream>>>(W1, root1, WT1);
    wt_kernel<<<(WTSZ + 255) / 256, 256, 0, stream>>>(W2, root2, WT2);

    fused_kernel<true, true><<<NBLK, 256, 0, stream>>>(emb, WT1, rp, perm, b1, hbf);
    fused_kernel<false, false><<<NBLK, 256, 0, stream>>>(hbf, WT2, rp, perm, b2, out);
}

// Round 6
// 1410.408 us; speedup vs baseline: 1.5366x; 1.5341x over previous
//
#include <hip/hip_runtime.h>
#include <cstdint>
#include <cstddef>

#define NNODES 50000
#define NREL   16
#define DIM    200
#define NEDGE  400000
#define NBLK   782                      // ceil(NNODES/64)
#define NKEY   (NBLK * 1024)            // 800768, key = (dst>>6)*1024 + r*64 + (dst&63)
#define NPART  (NKEY / 256)             // 3128
#define WTN    208                      // padded n (13 x 16)
#define WTK    224                      // padded k (7 x 32)
#define WTSZ   (17 * WTN * WTK)
#define MAXB   10                       // batched gathers per round (wave-chunk deg: Poisson λ=8)

typedef __attribute__((ext_vector_type(8))) short short8;   // 8 bf16
typedef __attribute__((ext_vector_type(4))) float floatx4;  // MFMA C/D

__device__ __forceinline__ unsigned short f2bf(float f) {
    unsigned int u = __float_as_uint(f);
    u = (u + 0x7FFFu + ((u >> 16) & 1u)) >> 16;   // RNE
    return (unsigned short)u;
}
__device__ __forceinline__ float bf2f(unsigned short h) {
    return __uint_as_float(((unsigned int)h) << 16);
}

// ---------- preprocessing: counting sort by block-major key ----------

__device__ __forceinline__ int edge_key(int d, int r) {
    return (d >> 6) * 1024 + r * 64 + (d & 63);
}

__global__ void count_kernel(const int* __restrict__ ei, const int* __restrict__ et,
                             int* __restrict__ cnt) {
    int e = blockIdx.x * 256 + threadIdx.x;
    if (e < NEDGE) atomicAdd(&cnt[edge_key(ei[NEDGE + e], et[e])], 1);
}

__global__ void scan1_kernel(const int* __restrict__ cnt, int* __restrict__ rp,
                             int* __restrict__ part) {
    __shared__ int sc[256];
    int b = blockIdx.x, t = threadIdx.x, i = b * 256 + t;
    int v = cnt[i];
    sc[t] = v; __syncthreads();
    for (int off = 1; off < 256; off <<= 1) {
        int x = (t >= off) ? sc[t - off] : 0;
        __syncthreads();
        sc[t] += x;
        __syncthreads();
    }
    int incl = sc[t];
    rp[i] = incl - v;
    if (t == 255) part[b] = incl;
}

__global__ void scan2_kernel(int* __restrict__ p) {
    __shared__ int sc[256];
    __shared__ int carry_s;
    int t = threadIdx.x;
    if (t == 0) carry_s = 0;
    __syncthreads();
    for (int base = 0; base < NPART; base += 256) {
        int i = base + t;
        int v = (i < NPART) ? p[i] : 0;
        sc[t] = v; __syncthreads();
        for (int off = 1; off < 256; off <<= 1) {
            int x = (t >= off) ? sc[t - off] : 0;
            __syncthreads();
            sc[t] += x;
            __syncthreads();
        }
        int incl = sc[t];
        int carry = carry_s;
        if (i < NPART) p[i] = carry + incl - v;
        __syncthreads();
        if (t == 255) carry_s = carry + incl;
        __syncthreads();
    }
    if (t == 0) p[NPART] = carry_s;   // == NEDGE
}

__global__ void scan3_kernel(int* __restrict__ rp, int* __restrict__ cursor,
                             const int* __restrict__ part) {
    int i = blockIdx.x * 256 + threadIdx.x;
    if (i < NKEY) {
        int v = rp[i] + part[i >> 8];
        rp[i] = v;
        cursor[i] = v;
    } else if (i == NKEY) {
        rp[i] = part[NPART];
    }
}

// perm[pos] = (row_in_block << 16) | src   (src < 50000 fits 16 bits)
__global__ void scatter_kernel(const int* __restrict__ ei, const int* __restrict__ et,
                               int* __restrict__ cursor, int* __restrict__ perm) {
    int e = blockIdx.x * 256 + threadIdx.x;
    if (e < NEDGE) {
        int d = ei[NEDGE + e];
        int pos = atomicAdd(&cursor[edge_key(d, et[e])], 1);
        perm[pos] = ((d & 63) << 16) | ei[e];
    }
}

// ---------- W^T prep: WT[r][n][k] bf16, zero-padded; r==16 is root ----------
__global__ void wt_kernel(const float* __restrict__ W, const float* __restrict__ root,
                          unsigned short* __restrict__ WT) {
    int idx = blockIdx.x * 256 + threadIdx.x;
    if (idx >= WTSZ) return;
    int r = idx / (WTN * WTK);
    int rem = idx - r * (WTN * WTK);
    int n = rem / WTK;
    int k = rem - n * WTK;
    float v = 0.f;
    if (n < DIM && k < DIM)
        v = (r < 16) ? W[((size_t)r * DIM + k) * DIM + n] : root[(size_t)k * DIM + n];
    WT[idx] = f2bf(v);
}

// ---------- fused layer ----------
// Wave owns 16 dst rows; NO barriers in the chunk loop (wave reads only its own
// As rows). Per chunk: 1 vector pm-load + readlane, <=MAXB independent row
// gathers in flight, run-length register accumulation (sorted by row), ushort4
// LDS writes, then MFMA. LDS = 25.7 KB -> 6 blocks/CU; VGPR<=128 -> 16 waves/CU.
template<bool SRC_F32, bool OUT_RELU_BF16>
__global__ __launch_bounds__(256, 4) void fused_kernel(
        const void* __restrict__ srcv, const unsigned short* __restrict__ WT,
        const int* __restrict__ rp, const int* __restrict__ perm,
        const float* __restrict__ bias, void* __restrict__ outv) {
    __shared__ __align__(16) char As[25664];   // 64 rows x 400 B bf16 + 64 B slack
    const int t = threadIdx.x;
    const int w = t >> 6;
    const int lane = t & 63;
    const int quad = lane >> 4;
    const int mn = lane & 15;
    const int v0 = blockIdx.x * 64;
    const int kbase = blockIdx.x * 1024;
    const bool colok = (lane < 50);

    // zero all of As once (also slack) so pad/garbage reads are finite
    for (int i = t; i < 25664 / 16; i += 256)
        *(float4*)(As + i * 16) = make_float4(0.f, 0.f, 0.f, 0.f);
    __syncthreads();   // only barrier in the kernel

    // per-chunk ranges for this wave: lane r (r<16) holds [b0,b1) of chunk r
    const int li = (lane < 16) ? lane : 15;
    const int b0 = rp[kbase + li * 64 + (w << 4)];
    const int b1 = rp[kbase + li * 64 + (w << 4) + 16];

    const float* srcf = (const float*)srcv;
    const unsigned short* srcb = (const unsigned short*)srcv;

    floatx4 acc[13];
    #pragma unroll
    for (int i = 0; i < 13; ++i) acc[i] = (floatx4){0.f, 0.f, 0.f, 0.f};

    auto do_mfma = [&](int r) {
        const char* WTr = (const char*)WT + (size_t)r * (WTN * WTK * 2);
        const char* arow = As + ((w << 4) + mn) * 400 + (quad << 4);
        const char* brow = WTr + (size_t)mn * (WTK * 2) + (quad << 4);
        for (int ks = 0; ks < 7; ++ks) {
            const short8 af = *(const short8*)(arow + ks * 64);
            #pragma unroll
            for (int nt = 0; nt < 13; ++nt) {
                const short8 bf = *(const short8*)(brow + ks * 64 + nt * (16 * WTK * 2));
                acc[nt] = __builtin_amdgcn_mfma_f32_16x16x32_bf16(af, bf, acc[nt], 0, 0, 0);
            }
        }
    };
    auto zero_rows = [&]() {   // zero this wave's 16 rows (6400 B)
        char* base = As + w * 6400;
        #pragma unroll
        for (int i = 0; i < 6; ++i)
            *(float4*)(base + i * 1024 + lane * 16) = make_float4(0.f, 0.f, 0.f, 0.f);
        if (lane < 16)
            *(float4*)(base + 6144 + lane * 16) = make_float4(0.f, 0.f, 0.f, 0.f);
    };

    for (int r = 0; r < NREL; ++r) {
        const int ws = __builtin_amdgcn_readlane(b0, r);
        const int we = __builtin_amdgcn_readlane(b1, r);
        if (ws >= we) continue;          // no edges: A rows zero -> contribution zero
        zero_rows();
        int curM = -1, curCnt = 0;
        float s0 = 0.f, s1 = 0.f, s2 = 0.f, s3 = 0.f;
        auto flush = [&]() {
            if (curM >= 0 && colok) {
                float sc = 1.0f / (float)curCnt;
                ushort4 pk;
                pk.x = f2bf(s0 * sc); pk.y = f2bf(s1 * sc);
                pk.z = f2bf(s2 * sc); pk.w = f2bf(s3 * sc);
                *(ushort4*)(As + curM * 400 + lane * 8) = pk;
            }
        };
        for (int jb = ws; jb < we; jb += MAXB) {
            const int nb = min(we - jb, MAXB);
            // one vector load covers up to MAXB edge descriptors
            const int pmv = perm[jb + ((lane < nb) ? lane : (nb - 1))];
            int pms[MAXB];
            #pragma unroll
            for (int i = 0; i < MAXB; ++i)
                pms[i] = __builtin_amdgcn_readlane(pmv, i);
            // issue all row gathers back-to-back (independent)
            float4  qf[MAXB];
            ushort4 qb[MAXB];
            #pragma unroll
            for (int i = 0; i < MAXB; ++i) {
                if (i < nb && colok) {
                    const int sv = pms[i] & 0xFFFF;
                    if (SRC_F32) qf[i] = *(const float4*)(srcf + (size_t)sv * DIM + (lane << 2));
                    else         qb[i] = *(const ushort4*)(srcb + (size_t)sv * DIM + (lane << 2));
                }
            }
            // drain in order: run-length accumulate (edges sorted by row)
            #pragma unroll
            for (int i = 0; i < MAXB; ++i) {
                if (i < nb) {
                    const int m = pms[i] >> 16;
                    float f0, f1, f2, f3;
                    if (SRC_F32) { f0 = qf[i].x; f1 = qf[i].y; f2 = qf[i].z; f3 = qf[i].w; }
                    else { f0 = bf2f(qb[i].x); f1 = bf2f(qb[i].y); f2 = bf2f(qb[i].z); f3 = bf2f(qb[i].w); }
                    if (m != curM) {
                        flush();
                        curM = m; curCnt = 1;
                        s0 = f0; s1 = f1; s2 = f2; s3 = f3;
                    } else {
                        ++curCnt;
                        s0 += f0; s1 += f1; s2 += f2; s3 += f3;
                    }
                }
            }
        }
        flush();
        do_mfma(r);
    }

    // root chunk: A = x rows directly (two batches of 8 independent loads)
    {
        zero_rows();
        #pragma unroll
        for (int g = 0; g < 2; ++g) {
            float4  qf[8];
            ushort4 qb[8];
            #pragma unroll
            for (int i = 0; i < 8; ++i) {
                const int v = v0 + (w << 4) + g * 8 + i;
                if (v < NNODES && colok) {
                    if (SRC_F32) qf[i] = *(const float4*)(srcf + (size_t)v * DIM + (lane << 2));
                    else         qb[i] = *(const ushort4*)(srcb + (size_t)v * DIM + (lane << 2));
                }
            }
            #pragma unroll
            for (int i = 0; i < 8; ++i) {
                const int m = (w << 4) + g * 8 + i;
                if (v0 + m < NNODES && colok) {
                    ushort4 pk;
                    if (SRC_F32) {
                        pk.x = f2bf(qf[i].x); pk.y = f2bf(qf[i].y);
                        pk.z = f2bf(qf[i].z); pk.w = f2bf(qf[i].w);
                    } else pk = qb[i];
                    *(ushort4*)(As + m * 400 + lane * 8) = pk;
                }
            }
        }
        do_mfma(16);
    }

    // epilogue: C row = quad*4 + i, col = nt*16 + mn
    float* outf = (float*)outv;
    unsigned short* outb = (unsigned short*)outv;
    #pragma unroll
    for (int nt = 0; nt < 13; ++nt) {
        const int col = nt * 16 + mn;
        if (col < DIM) {
            const float bv = bias[col];
            #pragma unroll
            for (int i = 0; i < 4; ++i) {
                const int v = v0 + (w << 4) + (quad << 2) + i;
                if (v < NNODES) {
                    float x = acc[nt][i] + bv;
                    if (OUT_RELU_BF16) {
                        x = fmaxf(x, 0.f);
                        outb[(size_t)v * DIM + col] = f2bf(x);
                    } else {
                        outf[(size_t)v * DIM + col] = x;
                    }
                }
            }
        }
    }
}

// ---------- launch ----------

extern "C" void kernel_launch(void* const* d_in, const int* in_sizes, int n_in,
                              void* d_out, int out_size, void* d_ws, size_t ws_size,
                              hipStream_t stream) {
    const int*   edge_index = (const int*)d_in[0];
    const int*   edge_type  = (const int*)d_in[1];
    const float* emb   = (const float*)d_in[2];
    const float* W1    = (const float*)d_in[3];
    const float* root1 = (const float*)d_in[4];
    const float* b1    = (const float*)d_in[5];
    const float* W2    = (const float*)d_in[6];
    const float* root2 = (const float*)d_in[7];
    const float* b2    = (const float*)d_in[8];
    float* out = (float*)d_out;

    // ws layout (bytes):
    //  cnt/cursor  0           3,203,072   (cnt dead after scan1; reused as cursor)
    //  rp          3,203,072   3,203,080
    //  part        6,406,152      12,520
    //  perm        6,418,672   1,600,000
    //  hbf         8,018,672  20,000,000
    //  WT1        28,018,672   1,584,128
    //  WT2        29,602,800   1,584,128   -> total ~31.2 MB
    char* ws = (char*)d_ws;
    int*            cnt    = (int*)(ws);
    int*            cursor = (int*)(ws);
    int*            rp     = (int*)(ws + 3203072);
    int*            part   = (int*)(ws + 6406152);
    int*            perm   = (int*)(ws + 6418672);
    unsigned short* hbf    = (unsigned short*)(ws + 8018672);
    unsigned short* WT1    = (unsigned short*)(ws + 28018672);
    unsigned short* WT2    = (unsigned short*)(ws + 29602800);

    hipMemsetAsync(cnt, 0, (size_t)NKEY * sizeof(int), stream);
    count_kernel<<<(NEDGE + 255) / 256, 256, 0, stream>>>(edge_index, edge_type, cnt);
    scan1_kernel<<<NPART, 256, 0, stream>>>(cnt, rp, part);
    scan2_kernel<<<1, 256, 0, stream>>>(part);
    scan3_kernel<<<(NKEY + 256) / 256 + 1, 256, 0, stream>>>(rp, cursor, part);
    scatter_kernel<<<(NEDGE + 255) / 256, 256, 0, stream>>>(edge_index, edge_type, cursor, perm);

    wt_kernel<<<(WTSZ + 255) / 256, 256, 0, stream>>>(W1, root1, WT1);
    wt_kernel<<<(WTSZ + 255) / 256, 256, 0, stream>>>(W2, root2, WT2);

    fused_kernel<true, true><<<NBLK, 256, 0, stream>>>(emb, WT1, rp, perm, b1, hbf);
    fused_kernel<false, false><<<NBLK, 256, 0, stream>>>(hbf, WT2, rp, perm, b2, out);
}